// Round 8
// baseline (394.993 us; speedup 1.0000x reference)
//
#include <hip/hip_runtime.h>

// LIF scan over T=16: mem_t = beta*mem + x_t - spk_{t-1}; spk_t = (mem_t - 1) > 0.
// One thread owns 4 neurons (float4) across all T. R1 structure (fastest
// measured: 91.6 us, plain stores, 2048 blocks) with ONE change:
// R8: stores are agent-scope (__hip_atomic_store relaxed) -> sc1 cache bits,
// bypassing the XCD-private L2 write/eviction chain (store->L2 dirty->evict to
// MALL->evict poison). Tests whether the L2 write path is what caps us at
// ~2.1 TB/s when D2D copy achieves 6.3 TB/s.
// History: R1/R3/R4/R6/R7 all ~2.0-2.4 TB/s across 8x variation in
// outstanding-request depth -> latency/MLP exonerated. nt-stores measured
// slower than plain (R3/R4/R6/R7 vs R1) -> dropped.

constexpr int   T      = 16;
constexpr float BETA   = 0.9f;
constexpr float THRESH = 1.0f;

typedef float f4 __attribute__((ext_vector_type(4)));

__global__ __launch_bounds__(256) void lif_kernel(const float* __restrict__ x,
                                                  float* __restrict__ out,
                                                  int n_per_t) {
    // No FMA contraction: must match numpy's two-rounding fp32 exactly, else
    // ~1-ulp drift flips spikes at the threshold (absmax = 1.0 cascades).
#pragma clang fp contract(off)
    const int idx = (blockIdx.x * blockDim.x + threadIdx.x) * 4;
    if (idx >= n_per_t) return;

    f4 mem = (f4)(0.f);
    f4 spk = (f4)(0.f);

#pragma unroll
    for (int t = 0; t < T; ++t) {
        const size_t off = (size_t)t * (size_t)n_per_t + (size_t)idx;
        const f4 xt = *reinterpret_cast<const f4*>(x + off);

#pragma unroll
        for (int j = 0; j < 4; ++j) {
            mem[j] = BETA * mem[j] + xt[j] - spk[j] * THRESH;
            spk[j] = (mem[j] - THRESH) > 0.f ? 1.f : 0.f;
        }

        // Agent-scope relaxed stores: sc1 set, write past XCD-private L2.
        float* o = out + off;
#pragma unroll
        for (int j = 0; j < 4; ++j) {
            __hip_atomic_store(o + j, spk[j], __ATOMIC_RELAXED,
                               __HIP_MEMORY_SCOPE_AGENT);
        }
    }
}

extern "C" void kernel_launch(void* const* d_in, const int* in_sizes, int n_in,
                              void* d_out, int out_size, void* d_ws, size_t ws_size,
                              hipStream_t stream) {
    const float* x   = (const float*)d_in[0];
    float*       out = (float*)d_out;

    const int total   = in_sizes[0];      // 33,554,432
    const int n_per_t = total / T;        // 2,097,152 (divisible by 4)
    const int threads = n_per_t / 4;      // 524,288

    dim3 block(256);
    dim3 grid((threads + block.x - 1) / block.x);  // 2048 blocks
    lif_kernel<<<grid, block, 0, stream>>>(x, out, n_per_t);
}